// Round 9
// baseline (181.103 us; speedup 1.0000x reference)
//
#include <hip/hip_runtime.h>
#include <hip/hip_bf16.h>
#include <math.h>

#define B 128
#define C 2048
#define N 196        // H*W
#define K 112
#define KB 113       // K + background
#define MROWS 128
#define XWROW 113
#define NCLS 200
#define CKC (C * K)
#define NT 13        // 13 tiles of 16 cols (208 >= 196)

#define OUT1_OFF 2834944
#define OUT2_OFF 2849280

typedef __attribute__((ext_vector_type(8))) short bf16x8;
typedef __attribute__((ext_vector_type(4))) float f32x4;

__device__ inline unsigned cvtpk(float a, float b) {
    union { __hip_bfloat162 h; unsigned u; } c;
    c.h.x = __float2bfloat16(a);
    c.h.y = __float2bfloat16(b);
    return c.u;
}
__device__ inline const float* row_src(int row, const float* concepts,
                                       const float* background, const float* wcfc) {
    if (row < K) return concepts + (size_t)row * C;
    if (row == K) return background;
    if (row == XWROW) return wcfc;
    return nullptr;
}

// ---------------------------------------------------------------------------
// asq_kernel: squared norms of rows 0..127
// ---------------------------------------------------------------------------
__global__ __launch_bounds__(256)
void asq_kernel(const float* __restrict__ concepts, const float* __restrict__ background,
                const float* __restrict__ wcfc, float* __restrict__ asq) {
    const int row = blockIdx.x;
    const int tid = threadIdx.x;
    const float* src = row_src(row, concepts, background, wcfc);
    float local = 0.f;
    if (src) for (int i = tid; i < C; i += 256) { float v = src[i]; local += v * v; }
    for (int off = 32; off; off >>= 1) local += __shfl_down(local, off);
    __shared__ float red[4];
    if ((tid & 63) == 0) red[tid >> 6] = local;
    __syncthreads();
    if (tid == 0) asq[row] = red[0] + red[1] + red[2] + red[3];
}

// ---------------------------------------------------------------------------
// pack_kernel: Afrag iteration-major: [it 0..31][f=2t+kw 0..15][lane][8 bf16]
//   lane l of frag (t,kw) at iter it holds A[16t+(l&15)][64it+32kw+8(l>>4)+j]
// ---------------------------------------------------------------------------
__global__ __launch_bounds__(64)
void pack_kernel(const float* __restrict__ concepts, const float* __restrict__ background,
                 const float* __restrict__ wcfc, unsigned short* __restrict__ Afrag) {
    const int t = blockIdx.x;       // 0..7 row tile
    const int kwg = blockIdx.y;     // 0..63 global k-window (32 wide)
    const int l = threadIdx.x;
    const int it = kwg >> 1, kw = kwg & 1;
    const int f = 2 * t + kw;
    const int row = 16 * t + (l & 15);
    const int kb = 32 * kwg + 8 * (l >> 4);
    const float* src = row_src(row, concepts, background, wcfc);
    unsigned o[4] = {0u, 0u, 0u, 0u};
    if (src) {
        const float4 f0 = *reinterpret_cast<const float4*>(src + kb);
        const float4 f1 = *reinterpret_cast<const float4*>(src + kb + 4);
        o[0] = cvtpk(f0.x, f0.y); o[1] = cvtpk(f0.z, f0.w);
        o[2] = cvtpk(f1.x, f1.y); o[3] = cvtpk(f1.z, f1.w);
    }
    *reinterpret_cast<uint4*>(Afrag + (((size_t)it * 16 + f) * 64 + l) * 8) =
        make_uint4(o[0], o[1], o[2], o[3]);
}

// ---------------------------------------------------------------------------
// wave_kernel: ONE independent wave per (b, 16-col tile). No barriers anywhere.
//   dots[128][16] = A(128x2048) @ x_b(2048x16) via MFMA, B-frags loaded
//   directly from global x (per-lane k-contiguous gather), A-frags streamed
//   from L2-resident Afrag. Wave-private softmax epilogue through 8.7KB LDS.
// ---------------------------------------------------------------------------
__global__ __launch_bounds__(64, 2)
void wave_kernel(const float* __restrict__ x,
                 const unsigned short* __restrict__ Afrag,
                 const float* __restrict__ asq_g,
                 float* __restrict__ out0,
                 float* __restrict__ lpart) {
    __shared__ float dl[MROWS][17];     // dots / L / a*xw scratch (pad 17: conflict-free)
    __shared__ float asq_s[MROWS];

    const int lane = threadIdx.x;
    const int nt = blockIdx.x;          // 0..12
    const int b = blockIdx.y;
    const int lo = lane & 15, hi = lane >> 4;
    const int col = nt * 16 + lo;
    const bool jv = col < N;
    const int colc = jv ? col : (N - 1);

    asq_s[lane] = asq_g[lane];
    asq_s[64 + lane] = asq_g[64 + lane];

    const float* xc = x + ((size_t)b * C + 8 * hi) * N + colc;   // lane's k-slice base
    const unsigned short* ab = Afrag + (size_t)lane * 8;

    f32x4 acc[8];
#pragma unroll
    for (int t = 0; t < 8; ++t) acc[t] = (f32x4){0.f, 0.f, 0.f, 0.f};
    float xs = 0.f;

    for (int it = 0; it < 32; ++it) {
        // 16 A-fragments: one contiguous 16KB chunk (L1/L2 streaming)
        bf16x8 af[16];
#pragma unroll
        for (int f = 0; f < 16; ++f)
            af[f] = *reinterpret_cast<const bf16x8*>(ab + ((size_t)it * 16 + f) * 512);
        // 16 x dwords: lane's B-fragment elements (k contiguous per lane)
        float xv[16];
#pragma unroll
        for (int kw = 0; kw < 2; ++kw)
#pragma unroll
            for (int j = 0; j < 8; ++j)
                xv[kw * 8 + j] = xc[(size_t)(64 * it + 32 * kw + j) * N];
#pragma unroll
        for (int e = 0; e < 16; ++e) xs += xv[e] * xv[e];
        union { unsigned u[4]; bf16x8 v; } b0, b1;
#pragma unroll
        for (int p = 0; p < 4; ++p) {
            b0.u[p] = cvtpk(xv[2 * p], xv[2 * p + 1]);
            b1.u[p] = cvtpk(xv[8 + 2 * p], xv[8 + 2 * p + 1]);
        }
#pragma unroll
        for (int t = 0; t < 8; ++t) {
            acc[t] = __builtin_amdgcn_mfma_f32_16x16x32_bf16(af[2 * t],     b0.v, acc[t], 0, 0, 0);
            acc[t] = __builtin_amdgcn_mfma_f32_16x16x32_bf16(af[2 * t + 1], b1.v, acc[t], 0, 0, 0);
        }
    }

    // acc -> dl ; C/D map: col=lane&15, row=16t+4*(lane>>4)+rr (m89-verified)
#pragma unroll
    for (int t = 0; t < 8; ++t)
#pragma unroll
        for (int rr = 0; rr < 4; ++rr)
            dl[16 * t + 4 * hi + rr][lo] = acc[t][rr];

    // xsq per column: lanes {lo, lo+16, lo+32, lo+48} hold disjoint k
    float xsq = xs + __shfl_xor(xs, 16);
    xsq += __shfl_xor(xsq, 32);

    // wave-private softmax over rows 0..112 of this lane's column
    const int rbeg = 29 * hi;
    const int rend = (rbeg + 29 < KB) ? rbeg + 29 : KB;

    float m = -3.4e38f;
    for (int r = rbeg; r < rend; ++r) {
        const float d2 = asq_s[r] + xsq - 2.f * dl[r][lo];
        const float L = -sqrtf(fmaxf(d2, 0.f));
        dl[r][lo] = L;
        m = fmaxf(m, L);
    }
    float M = fmaxf(m, __shfl_xor(m, 16));
    M = fmaxf(M, __shfl_xor(M, 32));

    float s = 0.f;
    for (int r = rbeg; r < rend; ++r) s += __expf(dl[r][lo] - M);
    float S = s + __shfl_xor(s, 16);
    S += __shfl_xor(S, 32);
    const float invS = 1.f / S;
    const float xw = dl[XWROW][lo];     // raw dot row 113

    float* o0 = out0 + (size_t)b * KB * N + col;
    for (int r = rbeg; r < rend; ++r) {
        const float a = __expf(dl[r][lo] - M) * invS;
        if (jv) o0[(size_t)r * N] = a;
        dl[r][lo] = (jv && r < K) ? a * xw : 0.f;   // prep lpart reduction
    }

    // lpart[b][nt][r] = sum over 16 cols of attn*xw  (rows 0..111)
    {
        float p = 0.f;
#pragma unroll
        for (int j = 0; j < 16; ++j) p += dl[lane][j];
        lpart[((size_t)b * NT + nt) * K + lane] = p;
        if (lane < K - 64) {
            float p2 = 0.f;
#pragma unroll
            for (int j = 0; j < 16; ++j) p2 += dl[64 + lane][j];
            lpart[((size_t)b * NT + nt) * K + 64 + lane] = p2;
        }
    }
}

// ---------------------------------------------------------------------------
// pq_kernel: R[o,k] = (concepts[k]-mod).w_lfc[o,k,:] ; Qs[o,k] = mod.w_lfc[o,k,:]
// ---------------------------------------------------------------------------
__global__ __launch_bounds__(256)
void pq_kernel(const float* __restrict__ wlfc, const float* __restrict__ concepts,
               const float* __restrict__ modulation,
               float* __restrict__ Rm, float* __restrict__ Qs) {
    const int wid = (blockIdx.x * 256 + threadIdx.x) >> 6;
    const int lane = threadIdx.x & 63;
    if (wid >= NCLS * K) return;
    const int o = wid / K;
    const int k = wid % K;
    const float4* wp = reinterpret_cast<const float4*>(wlfc + (size_t)o * CKC + (size_t)k * C);
    const float4* cp = reinterpret_cast<const float4*>(concepts + (size_t)k * C);
    const float4* mp = reinterpret_cast<const float4*>(modulation);
    float s1 = 0.f, s2 = 0.f;
#pragma unroll
    for (int it = 0; it < 8; ++it) {
        const int idx = it * 64 + lane;
        const float4 w4 = wp[idx];
        const float4 c4 = cp[idx];
        const float4 m4 = mp[idx];
        s1 += w4.x * c4.x + w4.y * c4.y + w4.z * c4.z + w4.w * c4.w;
        s2 += w4.x * m4.x + w4.y * m4.y + w4.z * m4.z + w4.w * m4.w;
    }
    for (int off = 32; off; off >>= 1) {
        s1 += __shfl_down(s1, off);
        s2 += __shfl_down(s2, off);
    }
    if (lane == 0) { Rm[wid] = s1 - s2; Qs[wid] = s2; }
}

// ---------------------------------------------------------------------------
// final_kernel: g = sigmoid(sum_13 lpart + b_cfc); label = b_lfc + sum_k g*R + Q
// ---------------------------------------------------------------------------
__global__ __launch_bounds__(256)
void final_kernel(const float* __restrict__ lpart, const float* __restrict__ bcfc,
                  const float* __restrict__ Rm, const float* __restrict__ Qs,
                  const float* __restrict__ blfc,
                  float* __restrict__ out1, float* __restrict__ out2) {
    const int b = blockIdx.x;
    const int tid = threadIdx.x;
    __shared__ float g_s[K];
    if (tid < K) {
        const float* lp = lpart + (size_t)b * NT * K + tid;
        float v = bcfc[0];
#pragma unroll
        for (int t = 0; t < NT; ++t) v += lp[(size_t)t * K];
        const float g = 1.f / (1.f + __expf(-v));
        out1[b * K + tid] = g;
        g_s[tid] = g;
    }
    __syncthreads();
    if (tid < NCLS) {
        float acc = blfc[tid];
        const float* rp = Rm + (size_t)tid * K;
        const float* qp = Qs + (size_t)tid * K;
        for (int k = 0; k < K; ++k) acc = fmaf(g_s[k], rp[k], acc) + qp[k];
        out2[b * NCLS + tid] = acc;
    }
}

extern "C" void kernel_launch(void* const* d_in, const int* in_sizes, int n_in,
                              void* d_out, int out_size, void* d_ws, size_t ws_size,
                              hipStream_t stream) {
    const float* x          = (const float*)d_in[0];
    const float* concepts   = (const float*)d_in[1];
    const float* modulation = (const float*)d_in[2];
    const float* background = (const float*)d_in[3];
    const float* wcfc       = (const float*)d_in[4];
    const float* bcfc       = (const float*)d_in[5];
    const float* wlfc       = (const float*)d_in[6];
    const float* blfc       = (const float*)d_in[7];

    float* out  = (float*)d_out;
    float* out0 = out;
    float* out1 = out + OUT1_OFF;
    float* out2 = out + OUT2_OFF;

    float* ws    = (float*)d_ws;
    float* asq   = ws;                               // 128
    float* lpart = asq + MROWS;                      // 128*13*112 = 186368
    float* Rm    = lpart + (size_t)B * NT * K;       // 22400
    float* Qs    = Rm + NCLS * K;                    // 22400
    unsigned short* Afrag = (unsigned short*)(Qs + NCLS * K);  // 512KB

    asq_kernel<<<MROWS, 256, 0, stream>>>(concepts, background, wcfc, asq);
    pack_kernel<<<dim3(8, 64), 64, 0, stream>>>(concepts, background, wcfc, Afrag);
    wave_kernel<<<dim3(NT, B), 64, 0, stream>>>(x, Afrag, asq, out0, lpart);
    pq_kernel<<<(NCLS * K) / 4, 256, 0, stream>>>(wlfc, concepts, modulation, Rm, Qs);
    final_kernel<<<B, 256, 0, stream>>>(lpart, bcfc, Rm, Qs, blfc, out1, out2);
}

// Round 11
// 112.047 us; speedup vs baseline: 1.6163x; 1.6163x over previous
//
#include <hip/hip_runtime.h>
#include <hip/hip_bf16.h>
#include <math.h>

#define B 128
#define C 2048
#define N 196
#define K 112
#define KB 113
#define MROWS 128
#define XWROW 113
#define NCLS 200
#define CKC (C * K)
#define NT 13          // 13 col-tiles of 16
#define MAIN_BLKS 416  // 1664 main waves / 4
#define PQ_BLKS 5600   // 22400 (o,k) wids / 4

#define OUT1_OFF 2834944
#define OUT2_OFF 2849280

typedef __attribute__((ext_vector_type(8))) short bf16x8;
typedef __attribute__((ext_vector_type(4))) float f32x4;

__device__ inline unsigned cvtpk(float a, float b) {
    union { __hip_bfloat162 h; unsigned u; } c;
    c.h.x = __float2bfloat16(a);
    c.h.y = __float2bfloat16(b);
    return c.u;
}
__device__ inline const float* row_src(int row, const float* concepts,
                                       const float* background, const float* wcfc) {
    if (row < K) return concepts + (size_t)row * C;
    if (row == K) return background;
    if (row == XWROW) return wcfc;
    return nullptr;
}
// fire-and-forget global->LDS DMA, 16B/lane; lds dest must be wave-uniform
__device__ __forceinline__ void gl16(const void* g, void* l) {
    __builtin_amdgcn_global_load_lds(
        (const __attribute__((address_space(1))) unsigned*)g,
        (__attribute__((address_space(3))) unsigned*)l, 16, 0, 0);
}

// ---------------------------------------------------------------------------
__global__ __launch_bounds__(256)
void asq_kernel(const float* __restrict__ concepts, const float* __restrict__ background,
                const float* __restrict__ wcfc, float* __restrict__ asq) {
    const int row = blockIdx.x;
    const int tid = threadIdx.x;
    const float* src = row_src(row, concepts, background, wcfc);
    float local = 0.f;
    if (src) for (int i = tid; i < C; i += 256) { float v = src[i]; local += v * v; }
    for (int off = 32; off; off >>= 1) local += __shfl_down(local, off);
    __shared__ float red[4];
    if ((tid & 63) == 0) red[tid >> 6] = local;
    __syncthreads();
    if (tid == 0) asq[row] = red[0] + red[1] + red[2] + red[3];
}

// ---------------------------------------------------------------------------
// pack: Afrag[it 0..63][f 0..7][lane][8 bf16]; lane l of (it,f) holds
//       A[16f+(l&15)][32it+8(l>>4)+j]  — linear DMA-ready stream
// ---------------------------------------------------------------------------
__global__ __launch_bounds__(64)
void pack_kernel(const float* __restrict__ concepts, const float* __restrict__ background,
                 const float* __restrict__ wcfc, unsigned short* __restrict__ Afrag) {
    const int f = blockIdx.x;       // 0..7 row tile
    const int it = blockIdx.y;      // 0..63 k-step
    const int l = threadIdx.x;
    const int row = 16 * f + (l & 15);
    const int kb = 32 * it + 8 * (l >> 4);
    const float* src = row_src(row, concepts, background, wcfc);
    unsigned o[4] = {0u, 0u, 0u, 0u};
    if (src) {
        const float4 f0 = *reinterpret_cast<const float4*>(src + kb);
        const float4 f1 = *reinterpret_cast<const float4*>(src + kb + 4);
        o[0] = cvtpk(f0.x, f0.y); o[1] = cvtpk(f0.z, f0.w);
        o[2] = cvtpk(f1.x, f1.y); o[3] = cvtpk(f1.z, f1.w);
    }
    *reinterpret_cast<uint4*>(Afrag + (((size_t)it * 8 + f) * 64 + l) * 8) =
        make_uint4(o[0], o[1], o[2], o[3]);
}

// ---------------------------------------------------------------------------
// fused_kernel:
//  blocks < MAIN_BLKS: 4 independent waves; wave = one (b, 16-col tile).
//    K-loop: A shared 4-buf ring (global_load_lds), x per-wave 4-buf ring
//    (global_load_lds), stage-ahead 2, counted vmcnt(8), ONE raw s_barrier/iter.
//    Epilogue: register/shuffle softmax, no LDS, no barriers.
//  blocks >= MAIN_BLKS: pq body (w_lfc sweep) — overlaps main's LDS/MFMA phase.
// ---------------------------------------------------------------------------
__global__ __launch_bounds__(256, 2)
void fused_kernel(const float* __restrict__ x,
                  const unsigned short* __restrict__ Afrag,
                  const float* __restrict__ asq_g,
                  float* __restrict__ out0,
                  float* __restrict__ lpart,
                  const float* __restrict__ wlfc,
                  const float* __restrict__ concepts,
                  const float* __restrict__ modulation,
                  float* __restrict__ Rm, float* __restrict__ Qs) {
    __shared__ __align__(16) char smem[65536];   // A ring 4x8KB | x rings 4 x (4x2KB)
    const int tid = threadIdx.x;
    const int lane = tid & 63;
    const int w = tid >> 6;
    const int blkid = blockIdx.x;

    if (blkid < MAIN_BLKS) {
        const int gw = blkid * 4 + w;
        const int b = gw / NT;
        const int nt = gw - b * NT;
        const int n0 = nt * 16;
        const int lo = lane & 15, hi = lane >> 4;

        char* Abase = smem;                       // shared across the 4 waves
        char* Xw = smem + 32768 + w * 8192;       // per-wave 4x2KB ring

        // ---- staging pointers ----
        const char* agl = (const char*)Afrag + w * 1024 + lane * 16;
        const int xr = lane >> 2, xc = lane & 3;
        const bool bad = (nt == NT - 1) && (xc != 0);   // cols >=196: garbage ok, keep in-bounds
        const float* xlane = bad ? x
            : x + (size_t)b * C * N + (size_t)xr * N + (n0 + xc * 4);
        const char* xgl = (const char*)xlane;

        f32x4 acc[8];
#pragma unroll
        for (int f = 0; f < 8; ++f) acc[f] = (f32x4){0.f, 0.f, 0.f, 0.f};
        float xs = 0.f;

#define STAGE(SBUF) do {                                                        \
        gl16(agl,        Abase + (SBUF) * 8192 + 0 * 4096 + w * 1024);          \
        gl16(agl + 4096, Abase + (SBUF) * 8192 + 1 * 4096 + w * 1024);          \
        gl16(xgl,                  Xw + (SBUF) * 2048);                         \
        gl16(xgl + 16 * N * 4,     Xw + (SBUF) * 2048 + 1024);                  \
        agl += 8192; xgl += (size_t)32 * N * 4;                                 \
    } while (0)

#define PIPE_WAIT(NSTR) do {                                                    \
        asm volatile("s_waitcnt vmcnt(" NSTR ")" ::: "memory");                 \
        __builtin_amdgcn_sched_barrier(0);                                      \
        __builtin_amdgcn_s_barrier();                                           \
        asm volatile("" ::: "memory");                                          \
        __builtin_amdgcn_sched_barrier(0);                                      \
    } while (0)

#define CONS(BUF) do {                                                          \
        bf16x8 af[8];                                                           \
        _Pragma("unroll")                                                       \
        for (int f = 0; f < 8; ++f)                                             \
            af[f] = *reinterpret_cast<const bf16x8*>(                           \
                Abase + (BUF) * 8192 + f * 1024 + (lane << 4));                 \
        float xv[8];                                                            \
        _Pragma("unroll")                                                       \
        for (int j = 0; j < 8; ++j)                                             \
            xv[j] = *reinterpret_cast<const float*>(                            \
                Xw + (BUF) * 2048 + ((hi * 8 + j) << 6) + (lo << 2));           \
        union { unsigned u[4]; bf16x8 v; } bu;                                  \
        _Pragma("unroll")                                                       \
        for (int p = 0; p < 4; ++p) bu.u[p] = cvtpk(xv[2 * p], xv[2 * p + 1]); \
        _Pragma("unroll")                                                       \
        for (int j = 0; j < 8; ++j) xs += xv[j] * xv[j];                        \
        _Pragma("unroll")                                                       \
        for (int f = 0; f < 8; ++f)                                             \
            acc[f] = __builtin_amdgcn_mfma_f32_16x16x32_bf16(                   \
                af[f], bu.v, acc[f], 0, 0, 0);                                  \
    } while (0)

        STAGE(0); STAGE(1);                       // prologue: iters 0,1 in flight
        for (int trip = 0; trip < 15; ++trip) {   // iters 0..59
            STAGE(2); PIPE_WAIT("8"); CONS(0);
            STAGE(3); PIPE_WAIT("8"); CONS(1);
            STAGE(0); PIPE_WAIT("8"); CONS(2);
            STAGE(1); PIPE_WAIT("8"); CONS(3);
        }
        STAGE(2); PIPE_WAIT("8"); CONS(0);        // t=60 (stage 62)
        STAGE(3); PIPE_WAIT("8"); CONS(1);        // t=61 (stage 63)
        PIPE_WAIT("4"); CONS(2);                  // t=62
        PIPE_WAIT("0"); CONS(3);                  // t=63

        // ---- register/shuffle epilogue (no LDS, no barriers) ----
        float xsq = xs + __shfl_xor(xs, 16);
        xsq += __shfl_xor(xsq, 32);
        // row 113 = 16*7 + 4*0 + 1 -> f=7, hi=0, rr=1: lanes 0..15, col = lane
        const float xw = __shfl(acc[7][1], lo);
        const int colg = n0 + lo;
        const bool colv = colg < N;

        float m = -3.4e38f;
#pragma unroll
        for (int f = 0; f < 8; ++f)
#pragma unroll
            for (int rr = 0; rr < 4; ++rr) {
                const int r = 16 * f + 4 * hi + rr;
                const bool valid = (f < 7) | ((hi == 0) & (rr == 0));
                if (valid) {
                    const float d2 = asq_g[r] + xsq - 2.f * acc[f][rr];
                    const float L = -sqrtf(fmaxf(d2, 0.f));
                    acc[f][rr] = L;
                    m = fmaxf(m, L);
                }
            }
        float M = fmaxf(m, __shfl_xor(m, 16));
        M = fmaxf(M, __shfl_xor(M, 32));
        float s = 0.f;
#pragma unroll
        for (int f = 0; f < 8; ++f)
#pragma unroll
            for (int rr = 0; rr < 4; ++rr) {
                const bool valid = (f < 7) | ((hi == 0) & (rr == 0));
                const float e = valid ? __expf(acc[f][rr] - M) : 0.f;
                acc[f][rr] = e;
                s += e;
            }
        float S = s + __shfl_xor(s, 16);
        S += __shfl_xor(S, 32);
        const float invS = 1.f / S;

        float* o0 = out0 + (size_t)b * KB * N + colg;
#pragma unroll
        for (int f = 0; f < 8; ++f)
#pragma unroll
            for (int rr = 0; rr < 4; ++rr) {
                const int r = 16 * f + 4 * hi + rr;
                const bool valid = (f < 7) | ((hi == 0) & (rr == 0));
                if (valid && colv) o0[(size_t)r * N] = acc[f][rr] * invS;
            }
        // lpart: rows < 112 only (f<7); butterfly sum over the 16 columns
#pragma unroll
        for (int f = 0; f < 7; ++f)
#pragma unroll
            for (int rr = 0; rr < 4; ++rr) {
                float pv = colv ? acc[f][rr] * invS * xw : 0.f;
                pv += __shfl_xor(pv, 1);
                pv += __shfl_xor(pv, 2);
                pv += __shfl_xor(pv, 4);
                pv += __shfl_xor(pv, 8);
                if (lo == 0)
                    lpart[((size_t)b * NT + nt) * K + 16 * f + 4 * hi + rr] = pv;
            }
    } else {
        // ---------------- pq body ----------------
        const int wid = (blkid - MAIN_BLKS) * 4 + w;   // < 22400
        const int o = wid / K;
        const int k = wid % K;
        const float4* wp = reinterpret_cast<const float4*>(wlfc + (size_t)o * CKC + (size_t)k * C);
        const float4* cp = reinterpret_cast<const float4*>(concepts + (size_t)k * C);
        const float4* mp = reinterpret_cast<const float4*>(modulation);
        float s1 = 0.f, s2 = 0.f;
#pragma unroll
        for (int it = 0; it < 8; ++it) {
            const int idx = it * 64 + lane;
            const float4 w4 = wp[idx];
            const float4 c4 = cp[idx];
            const float4 m4 = mp[idx];
            s1 += w4.x * c4.x + w4.y * c4.y + w4.z * c4.z + w4.w * c4.w;
            s2 += w4.x * m4.x + w4.y * m4.y + w4.z * m4.z + w4.w * m4.w;
        }
        for (int off = 32; off; off >>= 1) {
            s1 += __shfl_down(s1, off);
            s2 += __shfl_down(s2, off);
        }
        if (lane == 0) { Rm[wid] = s1 - s2; Qs[wid] = s2; }
    }
}

// ---------------------------------------------------------------------------
__global__ __launch_bounds__(256)
void final_kernel(const float* __restrict__ lpart, const float* __restrict__ bcfc,
                  const float* __restrict__ Rm, const float* __restrict__ Qs,
                  const float* __restrict__ blfc,
                  float* __restrict__ out1, float* __restrict__ out2) {
    const int b = blockIdx.x;
    const int tid = threadIdx.x;
    __shared__ float g_s[K];
    if (tid < K) {
        const float* lp = lpart + (size_t)b * NT * K + tid;
        float v = bcfc[0];
#pragma unroll
        for (int t = 0; t < NT; ++t) v += lp[(size_t)t * K];
        const float g = 1.f / (1.f + __expf(-v));
        out1[b * K + tid] = g;
        g_s[tid] = g;
    }
    __syncthreads();
    if (tid < NCLS) {
        float acc = blfc[tid];
        const float* rp = Rm + (size_t)tid * K;
        const float* qp = Qs + (size_t)tid * K;
        for (int k = 0; k < K; ++k) acc = fmaf(g_s[k], rp[k], acc) + qp[k];
        out2[b * NCLS + tid] = acc;
    }
}

extern "C" void kernel_launch(void* const* d_in, const int* in_sizes, int n_in,
                              void* d_out, int out_size, void* d_ws, size_t ws_size,
                              hipStream_t stream) {
    const float* x          = (const float*)d_in[0];
    const float* concepts   = (const float*)d_in[1];
    const float* modulation = (const float*)d_in[2];
    const float* background = (const float*)d_in[3];
    const float* wcfc       = (const float*)d_in[4];
    const float* bcfc       = (const float*)d_in[5];
    const float* wlfc       = (const float*)d_in[6];
    const float* blfc       = (const float*)d_in[7];

    float* out  = (float*)d_out;
    float* out0 = out;
    float* out1 = out + OUT1_OFF;
    float* out2 = out + OUT2_OFF;

    float* ws    = (float*)d_ws;
    float* asq   = ws;                               // 128
    float* lpart = asq + MROWS;                      // 128*13*112
    float* Rm    = lpart + (size_t)B * NT * K;       // 22400
    float* Qs    = Rm + NCLS * K;                    // 22400
    unsigned short* Afrag = (unsigned short*)(Qs + NCLS * K);  // 512KB

    asq_kernel<<<MROWS, 256, 0, stream>>>(concepts, background, wcfc, asq);
    pack_kernel<<<dim3(8, 64), 64, 0, stream>>>(concepts, background, wcfc, Afrag);
    fused_kernel<<<MAIN_BLKS + PQ_BLKS, 256, 0, stream>>>(
        x, Afrag, asq, out0, lpart, wlfc, concepts, modulation, Rm, Qs);
    final_kernel<<<B, 256, 0, stream>>>(lpart, bcfc, Rm, Qs, blfc, out1, out2);
}